// Round 5
// baseline (421.405 us; speedup 1.0000x reference)
//
#include <hip/hip_runtime.h>
#include <hip/hip_bf16.h>

#define NROWS 16384
#define MCOLS 4096
#define DDIM  128
#define LOG2E 1.4426950408889634f

typedef __attribute__((ext_vector_type(8))) short short8;
typedef __attribute__((ext_vector_type(4))) float f32x4;

__device__ __forceinline__ float wave_reduce_add(float d) {
#pragma unroll
  for (int off = 32; off >= 1; off >>= 1) d += __shfl_xor(d, off, 64);
  return d;
}

__device__ __forceinline__ float pcalc(float t, int m) {
  float u = fmaxf(t, 0.2f * t);   // leaky_relu (commutes with positive log2e scaling)
  float e = exp2f(u);             // inputs pre-scaled by log2e
  return m != 0 ? e : 0.f;
}

// round-to-nearest-even f32 -> bf16 (valid for finite non-NaN inputs)
__device__ __forceinline__ unsigned short f2bf(float f) {
  unsigned u = __builtin_bit_cast(unsigned, f);
  return (unsigned short)((u + 0x7fffu + ((u >> 16) & 1u)) >> 16);
}

__device__ __forceinline__ unsigned pack_bf2(float lo, float hi) {
  return (unsigned)f2bf(lo) | ((unsigned)f2bf(hi) << 16);
}

// ---------------------------------------------------------------------------
// K1: s_neigh' = (V @ a_neigh)*log2e ; pack V -> bf16 in MFMA-B fragment order.
// chunkid = kt*16 + (ks2*8 + cf); entry = chunkid*64 + lane holds B[k][col]
// for k = kt*64 + ks2*32 + (lane>>4)*8 + b (b=0..7), col = cf*16 + (lane&15).
// ---------------------------------------------------------------------------
__global__ __launch_bounds__(256) void aggr_prep(
    const float* __restrict__ V, const float* __restrict__ a,
    float* __restrict__ sneigh, short* __restrict__ packedV) {
  const int t = threadIdx.x, lane = t & 63, w = t >> 6;
  const int blk = blockIdx.x;  // 0..255

  float a0 = a[DDIM + 2 * lane] * LOG2E;
  float a1 = a[DDIM + 2 * lane + 1] * LOG2E;
#pragma unroll
  for (int i = 0; i < 4; ++i) {
    int j = blk * 16 + w * 4 + i;
    float2 v = *(const float2*)(V + (long)j * DDIM + 2 * lane);
    float d = wave_reduce_add(v.x * a0 + v.y * a1);
    if (lane == 0) sneigh[j] = d;
  }

  const int tg = blk * 256 + t;       // == chunkid*64 + lane
  const int l = tg & 63;
  const int chunkid = tg >> 6;        // 0..1023
  const int c = chunkid & 15, kt = chunkid >> 4;
  const int ks2 = c >> 3, cf = c & 7;
  const int col = cf * 16 + (l & 15);
  const long krow = (long)kt * 64 + ks2 * 32 + (l >> 4) * 8;
  short8 o;
#pragma unroll
  for (int b = 0; b < 8; ++b) {
    float f = V[(krow + b) * DDIM + col];
    o[b] = (short)f2bf(f);
  }
  *(short8*)(packedV + (long)tg * 8) = o;
}

// ---------------------------------------------------------------------------
// K2: main. 256 blocks x 256 threads (4 waves, NO K-split). Wave w owns 16
// rows, full K (64 iters of 64 cols). LDS = 48.5 KB -> 3 blocks/CU, 12
// waves/CU, 3 independent barrier domains per CU (keeps the HBM read queue
// full vs the old single 114 KB / 1-block/CU barrier-coupled design).
// Per iter: [STAGE next tile | fence | mask prefetch | fence] -> P + 16 MFMA
// -> s_waitcnt vmcnt(4) (stage retired, mask stays in flight) -> s_barrier.
// Epilogue all in-register (shfl) + direct store.
// ---------------------------------------------------------------------------
__global__ __launch_bounds__(256, 3) void aggr_main(
    const float* __restrict__ self_feats, const int* __restrict__ nm,
    const float* __restrict__ a, const float* __restrict__ sneigh,
    const short* __restrict__ packedV, float* __restrict__ out) {
  __shared__ float s_sn[MCOLS];                    // 16 KB: s_neigh'
  __shared__ float s_ss[64];                       // s_self' for block rows
  __shared__ __align__(16) short Bst[2][8192];     // 32 KB: [dbuf][16KB tile]

  const int t = threadIdx.x, lane = t & 63, w = t >> 6;  // w = 0..3
  const int blk = blockIdx.x;
  const int rowblk = blk * 64;
  const int arow = lane & 15, kg = lane >> 4;

  // s_self' : 16 rows per wave
  {
    float a0 = a[2 * lane] * LOG2E, a1 = a[2 * lane + 1] * LOG2E;
#pragma unroll
    for (int i = 0; i < 16; ++i) {
      int r = w * 16 + i;
      float2 v = *(const float2*)(self_feats + (long)(rowblk + r) * DDIM + 2 * lane);
      float d = wave_reduce_add(v.x * a0 + v.y * a1);
      if (lane == 0) s_ss[r] = d;
    }
  }
  // s_neigh' -> LDS (coalesced, 4 float4 per thread)
  {
    const float4* src = (const float4*)sneigh;
    float4* dst = (float4*)s_sn;
    dst[t] = src[t];
    dst[t + 256] = src[t + 256];
    dst[t + 512] = src[t + 512];
    dst[t + 768] = src[t + 768];
  }

  // stage one full K-tile (16 chunks of 1KB) into LDS; 4 chunks per wave
  auto STAGE = [&](int buf, int kt) {
#pragma unroll
    for (int j = 0; j < 4; ++j) {
      int c = w * 4 + j;
      const short* g = packedV + ((long)(kt * 16 + c) * 64 + lane) * 8;
      __builtin_amdgcn_global_load_lds(
          (const __attribute__((address_space(1))) void*)g,
          (__attribute__((address_space(3))) void*)(&Bst[buf][c * 512]),
          16, 0, 0);
    }
  };

  const int* mbase = nm + (long)(rowblk + w * 16 + arow) * MCOLS + kg * 8;

  int4 mc[4], mn[4] = {};
  STAGE(0, 0);
#pragma unroll
  for (int ks2 = 0; ks2 < 2; ++ks2)
#pragma unroll
    for (int q = 0; q < 2; ++q)
      mc[ks2 * 2 + q] = *(const int4*)(mbase + ks2 * 32 + q * 4);
  __syncthreads();  // prologue: covers s_ss, s_sn writes and STAGE(0,0)

  const float si = s_ss[w * 16 + arow];

  f32x4 acc[8];
#pragma unroll
  for (int i = 0; i < 8; ++i) acc[i] = (f32x4){0.f, 0.f, 0.f, 0.f};
  float den = 0.f;

#pragma unroll 2
  for (int it = 0; it < 64; ++it) {
    const int buf = it & 1;
    if (it < 63) {
      STAGE(buf ^ 1, it + 1);
      __builtin_amdgcn_sched_barrier(0);  // pin: STAGE issued before mask loads
#pragma unroll
      for (int ks2 = 0; ks2 < 2; ++ks2)
#pragma unroll
        for (int q = 0; q < 2; ++q)
          mn[ks2 * 2 + q] = *(const int4*)(mbase + (it + 1) * 64 + ks2 * 32 + q * 4);
      __builtin_amdgcn_sched_barrier(0);  // pin: mask loads issued here
    }

    short8 afr[2];
#pragma unroll
    for (int ks2 = 0; ks2 < 2; ++ks2) {
      const float* sj = &s_sn[it * 64 + ks2 * 32 + kg * 8];
      float4 s0 = *(const float4*)sj;
      float4 s1 = *(const float4*)(sj + 4);
      int4 m0 = mc[ks2 * 2], m1 = mc[ks2 * 2 + 1];
      float p0 = pcalc(si + s0.x, m0.x);
      float p1 = pcalc(si + s0.y, m0.y);
      float p2 = pcalc(si + s0.z, m0.z);
      float p3 = pcalc(si + s0.w, m0.w);
      float p4 = pcalc(si + s1.x, m1.x);
      float p5 = pcalc(si + s1.y, m1.y);
      float p6 = pcalc(si + s1.z, m1.z);
      float p7 = pcalc(si + s1.w, m1.w);
      den += ((p0 + p1) + (p2 + p3)) + ((p4 + p5) + (p6 + p7));
      int4 ai;
      ai.x = (int)pack_bf2(p0, p1);
      ai.y = (int)pack_bf2(p2, p3);
      ai.z = (int)pack_bf2(p4, p5);
      ai.w = (int)pack_bf2(p6, p7);
      afr[ks2] = __builtin_bit_cast(short8, ai);
    }

    const short8* Bks = (const short8*)&Bst[buf][0];
#pragma unroll
    for (int cf = 0; cf < 8; ++cf) {
      acc[cf] = __builtin_amdgcn_mfma_f32_16x16x32_bf16(afr[0], Bks[cf * 64 + lane], acc[cf], 0, 0, 0);
      acc[cf] = __builtin_amdgcn_mfma_f32_16x16x32_bf16(afr[1], Bks[(8 + cf) * 64 + lane], acc[cf], 0, 0, 0);
    }

    // Own STAGE (4 oldest in flight) retired; the 4 mask loads stay
    // outstanding across the barrier. At it==63 nothing is in flight: no-op.
    asm volatile("s_waitcnt vmcnt(4)" ::: "memory");
    __builtin_amdgcn_sched_barrier(0);
    __builtin_amdgcn_s_barrier();
    mc[0] = mn[0]; mc[1] = mn[1]; mc[2] = mn[2]; mc[3] = mn[3];
  }

  // den: sum over the 4 k-groups -> every lane holds den(row = arow)
  den += __shfl_xor(den, 16, 64);
  den += __shfl_xor(den, 32, 64);

  // redistribute: lane needs den of output rows kg*4+r (r=0..3)
  float rcp[4];
#pragma unroll
  for (int r = 0; r < 4; ++r) {
    float dv = __shfl(den, kg * 4 + r, 64);
    rcp[r] = dv > 0.f ? 1.0f / dv : 0.f;
  }
#pragma unroll
  for (int cf = 0; cf < 8; ++cf)
#pragma unroll
    for (int r = 0; r < 4; ++r)
      out[(long)(rowblk + w * 16 + kg * 4 + r) * DDIM + cf * 16 + arow] =
          acc[cf][r] * rcp[r];
}

extern "C" void kernel_launch(void* const* d_in, const int* in_sizes, int n_in,
                              void* d_out, int out_size, void* d_ws, size_t ws_size,
                              hipStream_t stream) {
  const float* self_feats = (const float*)d_in[0];
  const float* V = (const float*)d_in[1];           // features_neighs
  const int* nm = (const int*)d_in[2];              // neigh_matrix
  const float* a = (const float*)d_in[3];
  float* out = (float*)d_out;

  float* sneigh = (float*)d_ws;                     // 16 KB @ 0
  short* packedV = (short*)((char*)d_ws + 16384);   // 1 MB @ 16 KB

  aggr_prep<<<256, 256, 0, stream>>>(V, a, sneigh, packedV);
  aggr_main<<<256, 256, 0, stream>>>(self_feats, nm, a, sneigh, packedV, out);
}

// Round 6
// 389.748 us; speedup vs baseline: 1.0812x; 1.0812x over previous
//
#include <hip/hip_runtime.h>
#include <hip/hip_bf16.h>

#define NROWS 16384
#define MCOLS 4096
#define DDIM  128
#define LOG2E 1.4426950408889634f

typedef __attribute__((ext_vector_type(8))) short short8;
typedef __attribute__((ext_vector_type(4))) float f32x4;

__device__ __forceinline__ float wave_reduce_add(float d) {
#pragma unroll
  for (int off = 32; off >= 1; off >>= 1) d += __shfl_xor(d, off, 64);
  return d;
}

__device__ __forceinline__ float pcalc(float t, int m) {
  float u = fmaxf(t, 0.2f * t);   // leaky_relu (commutes with positive log2e scaling)
  float e = exp2f(u);             // inputs pre-scaled by log2e
  return m != 0 ? e : 0.f;
}

// round-to-nearest-even f32 -> bf16 (valid for finite non-NaN inputs)
__device__ __forceinline__ unsigned short f2bf(float f) {
  unsigned u = __builtin_bit_cast(unsigned, f);
  return (unsigned short)((u + 0x7fffu + ((u >> 16) & 1u)) >> 16);
}

__device__ __forceinline__ unsigned pack_bf2(float lo, float hi) {
  return (unsigned)f2bf(lo) | ((unsigned)f2bf(hi) << 16);
}

// ---------------------------------------------------------------------------
// K1: s_neigh' = (V @ a_neigh)*log2e ; pack V -> bf16 in MFMA-B fragment order.
// chunkid = kt*16 + (ks2*8 + cf); entry = chunkid*64 + lane holds B[k][col]
// for k = kt*64 + ks2*32 + (lane>>4)*8 + b (b=0..7), col = cf*16 + (lane&15).
// ---------------------------------------------------------------------------
__global__ __launch_bounds__(256) void aggr_prep(
    const float* __restrict__ V, const float* __restrict__ a,
    float* __restrict__ sneigh, short* __restrict__ packedV) {
  const int t = threadIdx.x, lane = t & 63, w = t >> 6;
  const int blk = blockIdx.x;  // 0..255

  float a0 = a[DDIM + 2 * lane] * LOG2E;
  float a1 = a[DDIM + 2 * lane + 1] * LOG2E;
#pragma unroll
  for (int i = 0; i < 4; ++i) {
    int j = blk * 16 + w * 4 + i;
    float2 v = *(const float2*)(V + (long)j * DDIM + 2 * lane);
    float d = wave_reduce_add(v.x * a0 + v.y * a1);
    if (lane == 0) sneigh[j] = d;
  }

  const int tg = blk * 256 + t;       // == chunkid*64 + lane
  const int l = tg & 63;
  const int chunkid = tg >> 6;        // 0..1023
  const int c = chunkid & 15, kt = chunkid >> 4;
  const int ks2 = c >> 3, cf = c & 7;
  const int col = cf * 16 + (l & 15);
  const long krow = (long)kt * 64 + ks2 * 32 + (l >> 4) * 8;
  short8 o;
#pragma unroll
  for (int b = 0; b < 8; ++b) {
    float f = V[(krow + b) * DDIM + col];
    o[b] = (short)f2bf(f);
  }
  *(short8*)(packedV + (long)tg * 8) = o;
}

// ---------------------------------------------------------------------------
// K2: main. 512 blocks x 256 threads. Block = 32 rows; 4 waves = 2 row-waves
// (rw) x 2 K-halves (ks, 2048 cols each = 32 iters of 64). LDS = 80 KB exactly
// (s_sn 16K + Bst 64K; epilogue comb overlays Bst) -> 2 blocks/CU, 8 waves/CU
// in 2 independent barrier domains. Mask ring-prefetched 3 iters deep (4-slot
// register ring, unroll-4 static). Per iter: STAGE(i+1) | MASK(i+3) | compute
// | vmcnt(4) (stage retired, newest mask stays in flight) | s_barrier.
// ---------------------------------------------------------------------------
#define BODY(I, SC, BUF, STG, MSK, VMC)                                        \
  {                                                                            \
    const int i_ = (I);                                                        \
    if (STG) STAGE((BUF) ^ 1, i_ + 1);                                         \
    __builtin_amdgcn_sched_barrier(0);                                         \
    if (MSK) MASK((((SC) + 3) & 3), i_ + 3);                                   \
    __builtin_amdgcn_sched_barrier(0);                                         \
    short8 afr[2];                                                             \
    _Pragma("unroll")                                                          \
    for (int ks2 = 0; ks2 < 2; ++ks2) {                                        \
      const float* sj = &s_sn[(ks * 32 + i_) * 64 + ks2 * 32 + kg * 8];        \
      float4 s0 = *(const float4*)sj;                                          \
      float4 s1 = *(const float4*)(sj + 4);                                    \
      int4 m0 = rg[SC][ks2 * 2], m1 = rg[SC][ks2 * 2 + 1];                     \
      float p0 = pcalc(si + s0.x, m0.x);                                       \
      float p1 = pcalc(si + s0.y, m0.y);                                       \
      float p2 = pcalc(si + s0.z, m0.z);                                       \
      float p3 = pcalc(si + s0.w, m0.w);                                       \
      float p4 = pcalc(si + s1.x, m1.x);                                       \
      float p5 = pcalc(si + s1.y, m1.y);                                       \
      float p6 = pcalc(si + s1.z, m1.z);                                       \
      float p7 = pcalc(si + s1.w, m1.w);                                       \
      den += ((p0 + p1) + (p2 + p3)) + ((p4 + p5) + (p6 + p7));                \
      int4 ai;                                                                 \
      ai.x = (int)pack_bf2(p0, p1);                                            \
      ai.y = (int)pack_bf2(p2, p3);                                            \
      ai.z = (int)pack_bf2(p4, p5);                                            \
      ai.w = (int)pack_bf2(p6, p7);                                            \
      afr[ks2] = __builtin_bit_cast(short8, ai);                               \
    }                                                                          \
    const short8* Bks = (const short8*)&Bst[BUF][ks][0];                       \
    _Pragma("unroll")                                                          \
    for (int cf = 0; cf < 8; ++cf) {                                           \
      acc[cf] = __builtin_amdgcn_mfma_f32_16x16x32_bf16(                       \
          afr[0], Bks[cf * 64 + lane], acc[cf], 0, 0, 0);                      \
      acc[cf] = __builtin_amdgcn_mfma_f32_16x16x32_bf16(                       \
          afr[1], Bks[(8 + cf) * 64 + lane], acc[cf], 0, 0, 0);                \
    }                                                                          \
    asm volatile("s_waitcnt vmcnt(" #VMC ")" ::: "memory");                    \
    __builtin_amdgcn_sched_barrier(0);                                         \
    __builtin_amdgcn_s_barrier();                                              \
    __builtin_amdgcn_sched_barrier(0);                                         \
  }

__global__ __launch_bounds__(256, 2) void aggr_main(
    const float* __restrict__ self_feats, const int* __restrict__ nm,
    const float* __restrict__ a, const float* __restrict__ sneigh,
    const short* __restrict__ packedV, float* __restrict__ out) {
  __shared__ float s_sn[MCOLS];                    // 16 KB: s_neigh'
  __shared__ __align__(16) short Bst[2][2][8192];  // 64 KB: [dbuf][ks][16KB]

  const int t = threadIdx.x, lane = t & 63, w = t >> 6;
  const int rw = w & 1, ks = w >> 1;
  const int rowblk = blockIdx.x * 32;
  const int arow = lane & 15, kg = lane >> 4;
  const int row = rowblk + rw * 16 + arow;

  // s_self' for this lane's row, via register dot + 2 shuffles (no LDS)
  float sip = 0.f;
  {
    const float* rp = self_feats + (long)row * DDIM + kg * 32;
    const float* ap = a + kg * 32;
#pragma unroll
    for (int j = 0; j < 8; ++j) {
      float4 v = *(const float4*)(rp + j * 4);
      float4 av = *(const float4*)(ap + j * 4);
      sip += v.x * av.x + v.y * av.y + v.z * av.z + v.w * av.w;
    }
  }
  sip += __shfl_xor(sip, 16, 64);
  sip += __shfl_xor(sip, 32, 64);
  const float si = sip * LOG2E;

  // s_neigh' -> LDS (coalesced, 4 float4 per thread)
  {
    const float4* src = (const float4*)sneigh;
    float4* dst = (float4*)s_sn;
#pragma unroll
    for (int j = 0; j < 4; ++j) dst[t + j * 256] = src[t + j * 256];
  }

  // stage tile (ks, i): 16 chunks of 1 KB; the 2 waves of this ks do 8 each
  auto STAGE = [&](int buf, int i) {
    int kt = ks * 32 + i;
#pragma unroll
    for (int j = 0; j < 8; ++j) {
      int c = rw * 8 + j;
      const short* g = packedV + ((long)(kt * 16 + c) * 64 + lane) * 8;
      __builtin_amdgcn_global_load_lds(
          (const __attribute__((address_space(1))) void*)g,
          (__attribute__((address_space(3))) void*)(&Bst[buf][ks][c * 512]),
          16, 0, 0);
    }
  };

  const int* mbase = nm + (long)row * MCOLS + ks * 2048 + kg * 8;
  int4 rg[4][4];  // 4-slot mask ring; all indices compile-time after unroll
  auto MASK = [&](int slot, int i) {
#pragma unroll
    for (int ks2 = 0; ks2 < 2; ++ks2)
#pragma unroll
      for (int q = 0; q < 2; ++q)
        rg[slot][ks2 * 2 + q] = *(const int4*)(mbase + i * 64 + ks2 * 32 + q * 4);
  };

  __builtin_amdgcn_sched_barrier(0);  // prologue loads issued before STAGE/MASK
  STAGE(0, 0);
  MASK(0, 0);
  MASK(1, 1);
  MASK(2, 2);
  __builtin_amdgcn_sched_barrier(0);
  asm volatile("s_waitcnt vmcnt(12)" ::: "memory");  // stage(0) retired
  __syncthreads();                                   // s_sn + Bst[0] ready
  asm volatile("s_waitcnt vmcnt(8)" ::: "memory");   // mask(0) retired

  f32x4 acc[8];
#pragma unroll
  for (int i = 0; i < 8; ++i) acc[i] = (f32x4){0.f, 0.f, 0.f, 0.f};
  float den = 0.f;

  for (int it = 0; it < 28; it += 4) {
    BODY(it + 0, 0, 0, true, true, 4)
    BODY(it + 1, 1, 1, true, true, 4)
    BODY(it + 2, 2, 0, true, true, 4)
    BODY(it + 3, 3, 1, true, true, 4)
  }
  BODY(28, 0, 0, true, true, 4)    // issues mask(31) into slot 3
  BODY(29, 1, 1, true, false, 0)
  BODY(30, 2, 0, true, false, 0)
  BODY(31, 3, 1, false, false, 0)
  __syncthreads();  // Bst dead; safe to overlay comb

  // den: sum the 4 kg groups -> every lane: den(row=arow) for its ks half
  den += __shfl_xor(den, 16, 64);
  den += __shfl_xor(den, 32, 64);

  float* comb = (float*)&Bst[0][0][0];  // [32][132] f32 + den_x, inside 64 KB
  float* den_x = comb + 32 * 132;
  if (ks == 1) {
#pragma unroll
    for (int cf = 0; cf < 8; ++cf)
#pragma unroll
      for (int r = 0; r < 4; ++r)
        comb[(rw * 16 + kg * 4 + r) * 132 + cf * 16 + arow] = acc[cf][r];
    if (lane < 16) den_x[rw * 16 + lane] = den;
  }
  __syncthreads();
  if (ks == 0) {
    float dtot = den + den_x[rw * 16 + arow];
    float rcp[4];
#pragma unroll
    for (int r = 0; r < 4; ++r) {
      float dv = __shfl(dtot, kg * 4 + r, 64);
      rcp[r] = dv > 0.f ? 1.0f / dv : 0.f;
    }
#pragma unroll
    for (int cf = 0; cf < 8; ++cf)
#pragma unroll
      for (int r = 0; r < 4; ++r)
        out[(long)(rowblk + rw * 16 + kg * 4 + r) * DDIM + cf * 16 + arow] =
            (acc[cf][r] + comb[(rw * 16 + kg * 4 + r) * 132 + cf * 16 + arow]) *
            rcp[r];
  }
}

extern "C" void kernel_launch(void* const* d_in, const int* in_sizes, int n_in,
                              void* d_out, int out_size, void* d_ws, size_t ws_size,
                              hipStream_t stream) {
  const float* self_feats = (const float*)d_in[0];
  const float* V = (const float*)d_in[1];           // features_neighs
  const int* nm = (const int*)d_in[2];              // neigh_matrix
  const float* a = (const float*)d_in[3];
  float* out = (float*)d_out;

  float* sneigh = (float*)d_ws;                     // 16 KB @ 0
  short* packedV = (short*)((char*)d_ws + 16384);   // 1 MB @ 16 KB

  aggr_prep<<<256, 256, 0, stream>>>(V, a, sneigh, packedV);
  aggr_main<<<512, 256, 0, stream>>>(self_feats, nm, a, sneigh, packedV, out);
}